// Round 3
// baseline (872.605 us; speedup 1.0000x reference)
//
#include <hip/hip_runtime.h>
#include <hip/hip_fp16.h>
#include <stdint.h>

#define B_ 8
#define N_ 16384
#define C_ 512
#define KS 8   // K-split for the Gram pass

typedef _Float16 h16;
typedef _Float16 half8 __attribute__((ext_vector_type(8)));
typedef float f32x4 __attribute__((ext_vector_type(4)));

// ---- async global->LDS, 16B/lane. Dest must be wave-uniform base + lane*16. ----
__device__ __forceinline__ void gload16(const void* g, void* l) {
  __builtin_amdgcn_global_load_lds(
      (const __attribute__((address_space(1))) uint32_t*)g,
      (__attribute__((address_space(3))) uint32_t*)l, 16, 0, 0);
}

// LDS tile layout for MFMA operands: [row][32 k] as 4 slots of 8 h16 (16 B),
// slot stored = seg ^ ((row>>1)&3)  (bank-conflict swizzle; source pre-swizzled,
// LDS linear, read applies the same involution -> both-sides-or-neither rule).
__device__ __forceinline__ half8 ldfrag(const h16* t, int r, int g) {
  return *(const half8*)(t + r * 32 + ((g ^ ((r >> 1) & 3)) << 3));
}

// ---------------- pass 0: transpose + fp16 hi/lo split ----------------
// x[b][n][c] f32  ->  xtH/xtL[bl][c][n] f16,  xh[bl][n][c] f16
__global__ __launch_bounds__(256) void k_prep(const float* __restrict__ x,
    h16* __restrict__ xtH, h16* __restrict__ xtL, h16* __restrict__ xh, int b0) {
  int bl = blockIdx.z, b = b0 + bl;
  int n0 = blockIdx.x << 6, c0 = blockIdx.y << 6;
  __shared__ __align__(16) h16 lh[64][70];  // stride 70 elems = 35 dwords (odd) -> ~2-way banks
  __shared__ __align__(16) h16 ll[64][70];
  int t = threadIdx.x;
  const float* xp = x + ((size_t)b * N_ + n0) * C_ + c0;
  h16* xhp = xh + ((size_t)bl * N_ + n0) * C_ + c0;
#pragma unroll
  for (int it = 0; it < 4; ++it) {
    int nr = (t >> 4) + (it << 4);
    int c4 = (t & 15) << 2;
    f32x4 v = *(const f32x4*)(xp + (size_t)nr * C_ + c4);
    h16 hv[4], lv[4];
#pragma unroll
    for (int u = 0; u < 4; ++u) {
      h16 h = (h16)v[u];
      hv[u] = h;
      lv[u] = (h16)(v[u] - (float)h);
    }
    union { h16 a[4]; uint2 u2; } ph;
    ph.a[0] = hv[0]; ph.a[1] = hv[1]; ph.a[2] = hv[2]; ph.a[3] = hv[3];
    *(uint2*)(xhp + (size_t)nr * C_ + c4) = ph.u2;
#pragma unroll
    for (int u = 0; u < 4; ++u) { lh[c4 + u][nr] = hv[u]; ll[c4 + u][nr] = lv[u]; }
  }
  __syncthreads();
  int cr = t >> 2, ns = (t & 3) << 4;
  size_t ob = ((size_t)bl * C_ + c0 + cr) * N_ + n0 + ns;
  uint32_t rh[8], rl[8];
#pragma unroll
  for (int e = 0; e < 8; ++e) {
    rh[e] = *(const uint32_t*)&lh[cr][ns + 2 * e];
    rl[e] = *(const uint32_t*)&ll[cr][ns + 2 * e];
  }
  *(uint4*)(xtH + ob)     = make_uint4(rh[0], rh[1], rh[2], rh[3]);
  *(uint4*)(xtH + ob + 8) = make_uint4(rh[4], rh[5], rh[6], rh[7]);
  *(uint4*)(xtL + ob)     = make_uint4(rl[0], rl[1], rl[2], rl[3]);
  *(uint4*)(xtL + ob + 8) = make_uint4(rl[4], rl[5], rl[6], rl[7]);
}

// ---------------- pass 1: E = Xt Xt^T with hi/lo split (3 MFMA chains) ----------------
// Upper-triangle 128x128 tiles (10 of 16), mirror-write the transpose.
__global__ __launch_bounds__(256) void k_gram(const h16* __restrict__ xtH,
    const h16* __restrict__ xtL, float* __restrict__ Ep, int nb) {
  int bl = blockIdx.z;
  int tp = blockIdx.x;
  int ti = 0, rem = tp;
  while (rem >= 4 - ti) { rem -= 4 - ti; ++ti; }
  int tj = ti + rem;
  int i0 = ti << 7, j0 = tj << 7;
  bool diag = (ti == tj);
  int k0 = blockIdx.y * (N_ / KS);
  __shared__ __align__(16) h16 lds[4 * 4096];  // Hi, Li, Hj, Lj tiles of [128][32]
  const h16* bHi = xtH + ((size_t)bl * C_ + i0) * N_;
  const h16* bLi = xtL + ((size_t)bl * C_ + i0) * N_;
  const h16* bHj = xtH + ((size_t)bl * C_ + j0) * N_;
  const h16* bLj = xtL + ((size_t)bl * C_ + j0) * N_;
  int tid = threadIdx.x, lane = tid & 63, wid = tid >> 6;
  int wr = (wid >> 1) << 6, wc = (wid & 1) << 6;
  int r16 = lane & 15, g = lane >> 4;
  f32x4 acc[4][4] = {};
  const h16* pHi = lds;
  const h16* pLi = lds + 4096;
  const h16* pHj = diag ? lds : lds + 8192;
  const h16* pLj = diag ? lds + 4096 : lds + 12288;
  int r0 = tid >> 2, s = tid & 3;
  int r1 = r0 + 64;
  int sx0 = (s ^ ((r0 >> 1) & 3)) << 3, sx1 = (s ^ ((r1 >> 1) & 3)) << 3;
  int d0 = r0 * 32 + s * 8, d1 = r1 * 32 + s * 8;
  for (int kc = 0; kc < N_ / KS / 32; ++kc) {
    int k = k0 + (kc << 5);
    __syncthreads();
    gload16(bHi + (size_t)r0 * N_ + k + sx0, (void*)(lds + d0));
    gload16(bHi + (size_t)r1 * N_ + k + sx1, (void*)(lds + d1));
    gload16(bLi + (size_t)r0 * N_ + k + sx0, (void*)(lds + 4096 + d0));
    gload16(bLi + (size_t)r1 * N_ + k + sx1, (void*)(lds + 4096 + d1));
    if (!diag) {
      gload16(bHj + (size_t)r0 * N_ + k + sx0, (void*)(lds + 8192 + d0));
      gload16(bHj + (size_t)r1 * N_ + k + sx1, (void*)(lds + 8192 + d1));
      gload16(bLj + (size_t)r0 * N_ + k + sx0, (void*)(lds + 12288 + d0));
      gload16(bLj + (size_t)r1 * N_ + k + sx1, (void*)(lds + 12288 + d1));
    }
    __syncthreads();
    half8 ahi[4], ali[4], bhj[4], blj[4];
#pragma unroll
    for (int m = 0; m < 4; ++m) {
      int ra = wr + (m << 4) + r16;
      int rb = wc + (m << 4) + r16;
      ahi[m] = ldfrag(pHi, ra, g);
      ali[m] = ldfrag(pLi, ra, g);
      bhj[m] = ldfrag(pHj, rb, g);
      blj[m] = ldfrag(pLj, rb, g);
    }
#pragma unroll
    for (int m = 0; m < 4; ++m)
#pragma unroll
      for (int n = 0; n < 4; ++n) {
        acc[m][n] = __builtin_amdgcn_mfma_f32_16x16x32_f16(ahi[m], bhj[n], acc[m][n], 0, 0, 0);
        acc[m][n] = __builtin_amdgcn_mfma_f32_16x16x32_f16(ahi[m], blj[n], acc[m][n], 0, 0, 0);
        acc[m][n] = __builtin_amdgcn_mfma_f32_16x16x32_f16(ali[m], bhj[n], acc[m][n], 0, 0, 0);
      }
  }
  float* e = Ep + ((size_t)(blockIdx.y * nb + bl) * C_) * C_;
#pragma unroll
  for (int m = 0; m < 4; ++m)
#pragma unroll
    for (int n = 0; n < 4; ++n)
#pragma unroll
      for (int q = 0; q < 4; ++q) {
        int i = i0 + wr + (m << 4) + (g << 2) + q;
        int j = j0 + wc + (n << 4) + r16;
        float v = acc[m][n][q];
        e[(size_t)i * C_ + j] = v;
        if (!diag) e[(size_t)j * C_ + i] = v;
      }
}

// ---------------- pass 2: softmax rows, fold gamma, write Wt = f16(gamma*A) ----------------
__global__ __launch_bounds__(256) void k_smax(const float* __restrict__ Ep,
    const float* __restrict__ gamma, h16* __restrict__ Wt, int nb) {
  int row = (blockIdx.x << 2) + (threadIdx.x >> 6);
  int lane = threadIdx.x & 63;
  int bl = row >> 9, i = row & 511;
  size_t st = (size_t)nb * C_ * C_;
  const float* e = Ep + ((size_t)bl * C_ + i) * C_;
  f32x4 a = *(const f32x4*)(e + (lane << 2));
  f32x4 b = *(const f32x4*)(e + 256 + (lane << 2));
#pragma unroll
  for (int kq = 1; kq < KS; ++kq) {
    a += *(const f32x4*)(e + kq * st + (lane << 2));
    b += *(const f32x4*)(e + kq * st + 256 + (lane << 2));
  }
  float mx = fmaxf(fmaxf(fmaxf(a[0], a[1]), fmaxf(a[2], a[3])),
                   fmaxf(fmaxf(b[0], b[1]), fmaxf(b[2], b[3])));
#pragma unroll
  for (int d = 32; d; d >>= 1) mx = fmaxf(mx, __shfl_xor(mx, d));
  f32x4 ta, tb;
#pragma unroll
  for (int u = 0; u < 4; ++u) { ta[u] = mx - a[u]; tb[u] = mx - b[u]; }  // reference's energy_new
  float tm = fmaxf(fmaxf(fmaxf(ta[0], ta[1]), fmaxf(ta[2], ta[3])),
                   fmaxf(fmaxf(tb[0], tb[1]), fmaxf(tb[2], tb[3])));
#pragma unroll
  for (int d = 32; d; d >>= 1) tm = fmaxf(tm, __shfl_xor(tm, d));
  f32x4 pa, pb;
#pragma unroll
  for (int u = 0; u < 4; ++u) { pa[u] = expf(ta[u] - tm); pb[u] = expf(tb[u] - tm); }
  float sm = pa[0] + pa[1] + pa[2] + pa[3] + pb[0] + pb[1] + pb[2] + pb[3];
#pragma unroll
  for (int d = 32; d; d >>= 1) sm += __shfl_xor(sm, d);
  float w = gamma[0] / sm;
  union { h16 a4[4]; uint2 u2; } o0, o1;
#pragma unroll
  for (int u = 0; u < 4; ++u) { o0.a4[u] = (h16)(pa[u] * w); o1.a4[u] = (h16)(pb[u] * w); }
  h16* wp = Wt + ((size_t)bl * C_ + i) * C_;
  *(uint2*)(wp + (lane << 2)) = o0.u2;
  *(uint2*)(wp + 256 + (lane << 2)) = o1.u2;
}

// ---------------- pass 3: y = xh @ Wt^T(row-stored) + x ----------------
__global__ __launch_bounds__(512) void k_out(const h16* __restrict__ xh,
    const h16* __restrict__ Wt, const float* __restrict__ x,
    float* __restrict__ y, int b0) {
  int bl = blockIdx.z, b = b0 + bl;
  int n0 = blockIdx.x << 7, c0 = blockIdx.y << 8;
  __shared__ __align__(16) h16 shA[4096];   // [128 n][32 k]
  __shared__ __align__(16) h16 shB[8192];   // [256 c][32 k]
  int tid = threadIdx.x, lane = tid & 63, wid = tid >> 6;
  int wn = (wid >> 2) << 6, wc = (wid & 3) << 6;
  int r16 = lane & 15, g = lane >> 4;
  const h16* bA = xh + ((size_t)bl * N_ + n0) * C_;
  const h16* bB = Wt + ((size_t)bl * C_ + c0) * C_;
  f32x4 acc[4][4] = {};
  int rA = tid >> 2, s4 = tid & 3;
  int rB1 = rA + 128;
  int sxA = (s4 ^ ((rA >> 1) & 3)) << 3;
  int sxB1 = (s4 ^ ((rB1 >> 1) & 3)) << 3;
  for (int kc = 0; kc < C_ / 32; ++kc) {
    int k = kc << 5;
    __syncthreads();
    gload16(bA + (size_t)rA * C_ + k + sxA, (void*)(shA + rA * 32 + s4 * 8));
    gload16(bB + (size_t)rA * C_ + k + sxA, (void*)(shB + rA * 32 + s4 * 8));
    gload16(bB + (size_t)rB1 * C_ + k + sxB1, (void*)(shB + rB1 * 32 + s4 * 8));
    __syncthreads();
    half8 af[4], bf[4];
#pragma unroll
    for (int m = 0; m < 4; ++m) {
      af[m] = ldfrag(shA, wn + (m << 4) + r16, g);
      bf[m] = ldfrag(shB, wc + (m << 4) + r16, g);
    }
#pragma unroll
    for (int m = 0; m < 4; ++m)
#pragma unroll
      for (int n = 0; n < 4; ++n)
        acc[m][n] = __builtin_amdgcn_mfma_f32_16x16x32_f16(af[m], bf[n], acc[m][n], 0, 0, 0);
  }
  const float* xp = x + ((size_t)b * N_ + n0) * C_;
  float* yp = y + ((size_t)b * N_ + n0) * C_;
#pragma unroll
  for (int m = 0; m < 4; ++m)
#pragma unroll
    for (int n = 0; n < 4; ++n)
#pragma unroll
      for (int q = 0; q < 4; ++q) {
        int nn = wn + (m << 4) + (g << 2) + q;
        size_t idx = (size_t)nn * C_ + c0 + wc + (n << 4) + r16;
        yp[idx] = acc[m][n][q] + xp[idx];
      }
}

extern "C" void kernel_launch(void* const* d_in, const int* in_sizes, int n_in,
                              void* d_out, int out_size, void* d_ws, size_t ws_size,
                              hipStream_t stream) {
  const float* x = (const float*)d_in[0];
  const float* gamma = (const float*)d_in[1];
  float* y = (float*)d_out;
  const size_t szXT = (size_t)C_ * N_ * sizeof(h16);         // 16 MiB / batch
  const size_t szXH = (size_t)N_ * C_ * sizeof(h16);         // 16 MiB
  const size_t szEP = (size_t)KS * C_ * C_ * sizeof(float);  // 8 MiB
  const size_t szWT = (size_t)C_ * C_ * sizeof(h16);         // 0.5 MiB
  const size_t per = 2 * szXT + szXH + szEP + szWT;
  int nb = B_;
  while (nb > 1 && (size_t)nb * per > ws_size) nb >>= 1;
  if (nb < 1) nb = 1;
  char* p = (char*)d_ws;
  h16* xtH = (h16*)p; p += (size_t)nb * szXT;
  h16* xtL = (h16*)p; p += (size_t)nb * szXT;
  h16* xh  = (h16*)p; p += (size_t)nb * szXH;
  float* Ep = (float*)p; p += (size_t)nb * szEP;
  h16* Wt  = (h16*)p;
  for (int b0 = 0; b0 < B_; b0 += nb) {
    k_prep<<<dim3(N_ / 64, C_ / 64, nb), 256, 0, stream>>>(x, xtH, xtL, xh, b0);
    k_gram<<<dim3(10, KS, nb), 256, 0, stream>>>(xtH, xtL, Ep, nb);
    k_smax<<<dim3(nb * (C_ / 4)), 256, 0, stream>>>(Ep, gamma, Wt, nb);
    k_out<<<dim3(N_ / 128, C_ / 256, nb), 512, 0, stream>>>(xh, Wt, x, y, b0);
  }
}

// Round 5
// 799.628 us; speedup vs baseline: 1.0913x; 1.0913x over previous
//
#include <hip/hip_runtime.h>
#include <hip/hip_fp16.h>
#include <stdint.h>

#define B_ 8
#define N_ 16384
#define C_ 512
#define KS 16   // K-split for the Gram pass (16 -> 1280 WGs = 5 blocks/CU residency)

typedef _Float16 h16;
typedef _Float16 half8 __attribute__((ext_vector_type(8)));
typedef float f32x4 __attribute__((ext_vector_type(4)));

// ---- async global->LDS, 16B/lane. Dest must be wave-uniform base + lane*16. ----
__device__ __forceinline__ void gload16(const void* g, void* l) {
  __builtin_amdgcn_global_load_lds(
      (const __attribute__((address_space(1))) uint32_t*)g,
      (__attribute__((address_space(3))) uint32_t*)l, 16, 0, 0);
}

// LDS tile layout for MFMA operands: [row][32 k] as 4 slots of 8 h16 (16 B),
// slot stored = seg ^ ((row>>1)&3). Source pre-swizzled, LDS linear, read applies
// the same involution. Verified conflict-free (SQ_LDS_BANK_CONFLICT = 0, R3).
__device__ __forceinline__ half8 ldfrag(const h16* t, int r, int g) {
  return *(const half8*)(t + r * 32 + ((g ^ ((r >> 1) & 3)) << 3));
}

// ---------------- pass 0: transpose + fp16 hi/lo split ----------------
// x[b][n][c] f32  ->  xtH/xtL[bl][c][n] f16,  xh[bl][n][c] f16
__global__ __launch_bounds__(256) void k_prep(const float* __restrict__ x,
    h16* __restrict__ xtH, h16* __restrict__ xtL, h16* __restrict__ xh, int b0) {
  int bl = blockIdx.z, b = b0 + bl;
  int n0 = blockIdx.x << 6, c0 = blockIdx.y << 6;
  __shared__ __align__(16) h16 lh[64][70];
  __shared__ __align__(16) h16 ll[64][70];
  int t = threadIdx.x;
  const float* xp = x + ((size_t)b * N_ + n0) * C_ + c0;
  h16* xhp = xh + ((size_t)bl * N_ + n0) * C_ + c0;
#pragma unroll
  for (int it = 0; it < 4; ++it) {
    int nr = (t >> 4) + (it << 4);
    int c4 = (t & 15) << 2;
    f32x4 v = *(const f32x4*)(xp + (size_t)nr * C_ + c4);
    h16 hv[4], lv[4];
#pragma unroll
    for (int u = 0; u < 4; ++u) {
      h16 h = (h16)v[u];
      hv[u] = h;
      lv[u] = (h16)(v[u] - (float)h);
    }
    union { h16 a[4]; uint2 u2; } ph;
    ph.a[0] = hv[0]; ph.a[1] = hv[1]; ph.a[2] = hv[2]; ph.a[3] = hv[3];
    *(uint2*)(xhp + (size_t)nr * C_ + c4) = ph.u2;
#pragma unroll
    for (int u = 0; u < 4; ++u) { lh[c4 + u][nr] = hv[u]; ll[c4 + u][nr] = lv[u]; }
  }
  __syncthreads();
  int cr = t >> 2, ns = (t & 3) << 4;
  size_t ob = ((size_t)bl * C_ + c0 + cr) * N_ + n0 + ns;
  uint32_t rh[8], rl[8];
#pragma unroll
  for (int e = 0; e < 8; ++e) {
    rh[e] = *(const uint32_t*)&lh[cr][ns + 2 * e];
    rl[e] = *(const uint32_t*)&ll[cr][ns + 2 * e];
  }
  *(uint4*)(xtH + ob)     = make_uint4(rh[0], rh[1], rh[2], rh[3]);
  *(uint4*)(xtH + ob + 8) = make_uint4(rh[4], rh[5], rh[6], rh[7]);
  *(uint4*)(xtL + ob)     = make_uint4(rl[0], rl[1], rl[2], rl[3]);
  *(uint4*)(xtL + ob + 8) = make_uint4(rl[4], rl[5], rl[6], rl[7]);
}

// ---------------- pass 1: E = Xt Xt^T with hi/lo split (3 MFMA chains) ----------------
// Upper-triangle 128x128 tiles (10 of 16), mirror-write the transpose.
// 1-D grid, XCD-swizzled: the 10 tiles sharing one (bl,kq) k-slice panel-set
// (2 MB, fits one XCD's 4 MB L2) are mapped to the SAME XCD for L2 reuse.
__global__ __launch_bounds__(256) void k_gram(const h16* __restrict__ xtH,
    const h16* __restrict__ xtL, float* __restrict__ Ep, int nb) {
  int NW = gridDim.x;                       // nb*KS*10, always % 8 == 0
  int b = blockIdx.x;
  int L = (b & 7) * (NW >> 3) + (b >> 3);   // bijective XCD-grouping swizzle
  int tp = L % 10;
  int pair = L / 10;
  int kq = pair & (KS - 1);
  int bl = pair / KS;
  int ti = 0, rem = tp;
  while (rem >= 4 - ti) { rem -= 4 - ti; ++ti; }
  int tj = ti + rem;
  int i0 = ti << 7, j0 = tj << 7;
  bool diag = (ti == tj);
  int k0 = kq * (N_ / KS);
  __shared__ __align__(16) h16 lds[4 * 4096];  // Hi, Li, Hj, Lj tiles of [128][32]
  const h16* bHi = xtH + ((size_t)bl * C_ + i0) * N_;
  const h16* bLi = xtL + ((size_t)bl * C_ + i0) * N_;
  const h16* bHj = xtH + ((size_t)bl * C_ + j0) * N_;
  const h16* bLj = xtL + ((size_t)bl * C_ + j0) * N_;
  int tid = threadIdx.x, lane = tid & 63, wid = tid >> 6;
  int wr = (wid >> 1) << 6, wc = (wid & 1) << 6;
  int r16 = lane & 15, g = lane >> 4;
  f32x4 acc[4][4] = {};
  const h16* pHi = lds;
  const h16* pLi = lds + 4096;
  const h16* pHj = diag ? lds : lds + 8192;
  const h16* pLj = diag ? lds + 4096 : lds + 12288;
  int r0 = tid >> 2, s = tid & 3;
  int r1 = r0 + 64;
  int sx0 = (s ^ ((r0 >> 1) & 3)) << 3, sx1 = (s ^ ((r1 >> 1) & 3)) << 3;
  int d0 = r0 * 32 + s * 8, d1 = r1 * 32 + s * 8;
  for (int kc = 0; kc < N_ / KS / 32; ++kc) {
    int k = k0 + (kc << 5);
    __syncthreads();
    gload16(bHi + (size_t)r0 * N_ + k + sx0, (void*)(lds + d0));
    gload16(bHi + (size_t)r1 * N_ + k + sx1, (void*)(lds + d1));
    gload16(bLi + (size_t)r0 * N_ + k + sx0, (void*)(lds + 4096 + d0));
    gload16(bLi + (size_t)r1 * N_ + k + sx1, (void*)(lds + 4096 + d1));
    if (!diag) {
      gload16(bHj + (size_t)r0 * N_ + k + sx0, (void*)(lds + 8192 + d0));
      gload16(bHj + (size_t)r1 * N_ + k + sx1, (void*)(lds + 8192 + d1));
      gload16(bLj + (size_t)r0 * N_ + k + sx0, (void*)(lds + 12288 + d0));
      gload16(bLj + (size_t)r1 * N_ + k + sx1, (void*)(lds + 12288 + d1));
    }
    __syncthreads();
    half8 ahi[4], ali[4], bhj[4], blj[4];
#pragma unroll
    for (int m = 0; m < 4; ++m) {
      int ra = wr + (m << 4) + r16;
      int rb = wc + (m << 4) + r16;
      ahi[m] = ldfrag(pHi, ra, g);
      ali[m] = ldfrag(pLi, ra, g);
      bhj[m] = ldfrag(pHj, rb, g);
      blj[m] = ldfrag(pLj, rb, g);
    }
#pragma unroll
    for (int m = 0; m < 4; ++m)
#pragma unroll
      for (int n = 0; n < 4; ++n) {
        acc[m][n] = __builtin_amdgcn_mfma_f32_16x16x32_f16(ahi[m], bhj[n], acc[m][n], 0, 0, 0);
        acc[m][n] = __builtin_amdgcn_mfma_f32_16x16x32_f16(ahi[m], blj[n], acc[m][n], 0, 0, 0);
        acc[m][n] = __builtin_amdgcn_mfma_f32_16x16x32_f16(ali[m], bhj[n], acc[m][n], 0, 0, 0);
      }
  }
  float* e = Ep + (size_t)(kq * nb + bl) * C_ * C_;
#pragma unroll
  for (int m = 0; m < 4; ++m)
#pragma unroll
    for (int n = 0; n < 4; ++n)
#pragma unroll
      for (int q = 0; q < 4; ++q) {
        int i = i0 + wr + (m << 4) + (g << 2) + q;
        int j = j0 + wc + (n << 4) + r16;
        float v = acc[m][n][q];
        e[(size_t)i * C_ + j] = v;
        if (!diag) e[(size_t)j * C_ + i] = v;
      }
}

// ---------------- pass 2: softmax rows, fold gamma, write Wt = f16(gamma*A) ----------------
__global__ __launch_bounds__(256) void k_smax(const float* __restrict__ Ep,
    const float* __restrict__ gamma, h16* __restrict__ Wt, int nb) {
  int row = (blockIdx.x << 2) + (threadIdx.x >> 6);
  int lane = threadIdx.x & 63;
  int bl = row >> 9, i = row & 511;
  size_t st = (size_t)nb * C_ * C_;
  const float* e = Ep + ((size_t)bl * C_ + i) * C_;
  f32x4 a = *(const f32x4*)(e + (lane << 2));
  f32x4 b = *(const f32x4*)(e + 256 + (lane << 2));
#pragma unroll
  for (int kq = 1; kq < KS; ++kq) {
    a += *(const f32x4*)(e + kq * st + (lane << 2));
    b += *(const f32x4*)(e + kq * st + 256 + (lane << 2));
  }
  float mx = fmaxf(fmaxf(fmaxf(a[0], a[1]), fmaxf(a[2], a[3])),
                   fmaxf(fmaxf(b[0], b[1]), fmaxf(b[2], b[3])));
#pragma unroll
  for (int d = 32; d; d >>= 1) mx = fmaxf(mx, __shfl_xor(mx, d));
  f32x4 ta, tb;
#pragma unroll
  for (int u = 0; u < 4; ++u) { ta[u] = mx - a[u]; tb[u] = mx - b[u]; }  // reference's energy_new
  float tm = fmaxf(fmaxf(fmaxf(ta[0], ta[1]), fmaxf(ta[2], ta[3])),
                   fmaxf(fmaxf(tb[0], tb[1]), fmaxf(tb[2], tb[3])));
#pragma unroll
  for (int d = 32; d; d >>= 1) tm = fmaxf(tm, __shfl_xor(tm, d));
  f32x4 pa, pb;
#pragma unroll
  for (int u = 0; u < 4; ++u) { pa[u] = expf(ta[u] - tm); pb[u] = expf(tb[u] - tm); }
  float sm = pa[0] + pa[1] + pa[2] + pa[3] + pb[0] + pb[1] + pb[2] + pb[3];
#pragma unroll
  for (int d = 32; d; d >>= 1) sm += __shfl_xor(sm, d);
  float w = gamma[0] / sm;
  union { h16 a4[4]; uint2 u2; } o0, o1;
#pragma unroll
  for (int u = 0; u < 4; ++u) { o0.a4[u] = (h16)(pa[u] * w); o1.a4[u] = (h16)(pb[u] * w); }
  h16* wp = Wt + ((size_t)bl * C_ + i) * C_;
  *(uint2*)(wp + (lane << 2)) = o0.u2;
  *(uint2*)(wp + 256 + (lane << 2)) = o1.u2;
}

// ---------------- pass 3: y = xh @ Wt^T(row-stored) + x ----------------
// 1-D grid, XCD-swizzled: the two c-tiles sharing one xh row-panel are adjacent.
__global__ __launch_bounds__(512) void k_out(const h16* __restrict__ xh,
    const h16* __restrict__ Wt, const float* __restrict__ x,
    float* __restrict__ y, int b0) {
  int NW = gridDim.x;
  int bswz = blockIdx.x;
  int L = (bswz & 7) * (NW >> 3) + (bswz >> 3);
  int bl = L >> 8;
  int rem2 = L & 255;
  int ct = rem2 & 1, nt = rem2 >> 1;
  int b = b0 + bl;
  int n0 = nt << 7, c0 = ct << 8;
  __shared__ __align__(16) h16 shA[4096];   // [128 n][32 k]
  __shared__ __align__(16) h16 shB[8192];   // [256 c][32 k]
  int tid = threadIdx.x, lane = tid & 63, wid = tid >> 6;
  int wn = (wid >> 2) << 6, wc = (wid & 3) << 6;
  int r16 = lane & 15, g = lane >> 4;
  const h16* bA = xh + ((size_t)bl * N_ + n0) * C_;
  const h16* bB = Wt + ((size_t)bl * C_ + c0) * C_;
  f32x4 acc[4][4] = {};
  int rA = tid >> 2, s4 = tid & 3;
  int rB1 = rA + 128;
  int sxA = (s4 ^ ((rA >> 1) & 3)) << 3;
  int sxB1 = (s4 ^ ((rB1 >> 1) & 3)) << 3;
  for (int kc = 0; kc < C_ / 32; ++kc) {
    int k = kc << 5;
    __syncthreads();
    gload16(bA + (size_t)rA * C_ + k + sxA, (void*)(shA + rA * 32 + s4 * 8));
    gload16(bB + (size_t)rA * C_ + k + sxA, (void*)(shB + rA * 32 + s4 * 8));
    gload16(bB + (size_t)rB1 * C_ + k + sxB1, (void*)(shB + rB1 * 32 + s4 * 8));
    __syncthreads();
    half8 af[4], bf[4];
#pragma unroll
    for (int m = 0; m < 4; ++m) {
      af[m] = ldfrag(shA, wn + (m << 4) + r16, g);
      bf[m] = ldfrag(shB, wc + (m << 4) + r16, g);
    }
#pragma unroll
    for (int m = 0; m < 4; ++m)
#pragma unroll
      for (int n = 0; n < 4; ++n)
        acc[m][n] = __builtin_amdgcn_mfma_f32_16x16x32_f16(af[m], bf[n], acc[m][n], 0, 0, 0);
  }
  const float* xp = x + ((size_t)b * N_ + n0) * C_;
  float* yp = y + ((size_t)b * N_ + n0) * C_;
#pragma unroll
  for (int m = 0; m < 4; ++m)
#pragma unroll
    for (int n = 0; n < 4; ++n)
#pragma unroll
      for (int q = 0; q < 4; ++q) {
        int nn = wn + (m << 4) + (g << 2) + q;
        size_t idx = (size_t)nn * C_ + c0 + wc + (n << 4) + r16;
        yp[idx] = acc[m][n][q] + xp[idx];
      }
}

extern "C" void kernel_launch(void* const* d_in, const int* in_sizes, int n_in,
                              void* d_out, int out_size, void* d_ws, size_t ws_size,
                              hipStream_t stream) {
  const float* x = (const float*)d_in[0];
  const float* gamma = (const float*)d_in[1];
  float* y = (float*)d_out;
  const size_t szXT = (size_t)C_ * N_ * sizeof(h16);         // 16 MiB / batch
  const size_t szXH = (size_t)N_ * C_ * sizeof(h16);         // 16 MiB
  const size_t szEP = (size_t)KS * C_ * C_ * sizeof(float);  // 16 MiB (KS=16)
  const size_t szWT = (size_t)C_ * C_ * sizeof(h16);         // 0.5 MiB
  const size_t per = 2 * szXT + szXH + szEP + szWT;
  int nb = B_;
  while (nb > 1 && (size_t)nb * per > ws_size) nb >>= 1;
  if (nb < 1) nb = 1;
  char* p = (char*)d_ws;
  h16* xtH = (h16*)p; p += (size_t)nb * szXT;
  h16* xtL = (h16*)p; p += (size_t)nb * szXT;
  h16* xh  = (h16*)p; p += (size_t)nb * szXH;
  float* Ep = (float*)p; p += (size_t)nb * szEP;
  h16* Wt  = (h16*)p;
  for (int b0 = 0; b0 < B_; b0 += nb) {
    k_prep<<<dim3(N_ / 64, C_ / 64, nb), 256, 0, stream>>>(x, xtH, xtL, xh, b0);
    k_gram<<<dim3(nb * KS * 10), 256, 0, stream>>>(xtH, xtL, Ep, nb);
    k_smax<<<dim3(nb * (C_ / 4)), 256, 0, stream>>>(Ep, gamma, Wt, nb);
    k_out<<<dim3(nb * 256), 512, 0, stream>>>(xh, Wt, x, y, b0);
  }
}